// Round 5
// baseline (363.940 us; speedup 1.0000x reference)
//
#include <hip/hip_runtime.h>
#include <math.h>

#define R_ROUTES 1152
#define N_CAPS 10
#define C_IN 8
#define D_DIM 16
#define B_BATCH 128
#define JD 160                      // N_CAPS * D_DIM
#define KK 9216                     // R_ROUTES * C_IN (GEMM K)
#define KSPLIT 32                   // 36 routes = 288 k per split
#define GRID 256                    // <= 1 block/CU: residency guaranteed

typedef __attribute__((ext_vector_type(8))) short short8;   // 8 bf16 (4 VGPRs)
typedef __attribute__((ext_vector_type(4))) float f32x4;    // MFMA accumulator

__device__ inline unsigned short f2bf(float f) {            // RNE fp32 -> bf16
    unsigned int u = __float_as_uint(f);
    unsigned int r = u + 0x7FFFu + ((u >> 16) & 1u);
    return (unsigned short)(r >> 16);
}
__device__ inline float bf2f(unsigned short h) {
    return __uint_as_float(((unsigned int)h) << 16);
}

// Device-scope grid barrier: monotonic counter, target = phase * GRID.
// Release on arrival flushes this block's stores (agent scope -> L2 writeback);
// acquire on the spin load invalidates L1/L2 so we see other XCDs' data.
__device__ inline void gridbar(unsigned int* cnt, unsigned int target) {
    __syncthreads();
    if (threadIdx.x == 0) {
        __hip_atomic_fetch_add(cnt, 1u, __ATOMIC_ACQ_REL, __HIP_MEMORY_SCOPE_AGENT);
        while (__hip_atomic_load(cnt, __ATOMIC_ACQUIRE, __HIP_MEMORY_SCOPE_AGENT) < target)
            __builtin_amdgcn_s_sleep(8);
    }
    __syncthreads();
}

// ---------------------------------------------------------------------------
// ws layout (byte offsets):
//   b_ij fp32 [1152][10]      @ 0
//   xh   bf16 [128][9216]     @ 46080      A-layout [b][k]
//   xl   bf16 [128][9216]     @ 2405376
//   xT   bf16 [9216][128]     @ 4764672    A-layout for agree ([rc][b])
//   vb   bf16 [160][128]      @ 7123968    B-layout for agree ([jd][b])
//   part fp32 [32][128][160]  @ 7164928    split-K partials (2.6 MB)
//   cnt  u32                  @ 9786368    grid-barrier counter
// Everything written before read each launch; cnt zeroed by k_init.
// ---------------------------------------------------------------------------

__global__ void k_init(unsigned int* cnt) {
    if (threadIdx.x == 0)
        __hip_atomic_store(cnt, 0u, __ATOMIC_RELAXED, __HIP_MEMORY_SCOPE_AGENT);
}

__global__ __launch_bounds__(256, 2) void k_main(
    const float* __restrict__ x, const float* __restrict__ W,
    unsigned short* __restrict__ xh, unsigned short* __restrict__ xl,
    unsigned short* __restrict__ xT, float* __restrict__ b_ij,
    unsigned short* __restrict__ vb, float* __restrict__ part,
    float* __restrict__ out, unsigned int* cnt) {
    int bid = blockIdx.x, t = threadIdx.x;
    __shared__ float tile[32][33];           // phase P
    __shared__ float cs36[36];               // phase I softmax (this block's cap)
    __shared__ unsigned short bhs[16][296];  // phase I staged c*W hi [jd_l][k_l]
    __shared__ unsigned short bls[16][296];
    __shared__ float m2[32][164];            // phase A M2 tile, +4 pad
    unsigned int tgt = 0;

    // ============ phase P: x -> bf16 hi/lo + transpose; zero b_ij ==========
    for (int job = bid; job < 1152; job += GRID) {
        int bx = job >> 2, by = job & 3;     // rc-tile 0..287, b-tile 0..3
        int tx = t & 31, ty = t >> 5;
        __syncthreads();                     // tile reuse across job loop
#pragma unroll
        for (int i = 0; i < 4; i++) {
            int row = ty + i * 8;            // b_local
            size_t idx = (size_t)(by * 32 + row) * KK + bx * 32 + tx;
            float v = x[idx];
            tile[row][tx] = v;
            unsigned short hi = f2bf(v);
            xh[idx] = hi;
            xl[idx] = f2bf(v - bf2f(hi));
        }
        __syncthreads();
#pragma unroll
        for (int i = 0; i < 4; i++) {
            int row = ty + i * 8;            // rc_local
            xT[(size_t)(bx * 32 + row) * B_BATCH + by * 32 + tx] = f2bf(tile[tx][row]);
        }
    }
    if (bid < 45) b_ij[bid * 256 + t] = 0.f; // 45*256 == 11520
    tgt += GRID; gridbar(cnt, tgt);

    for (int it = 0; it < 3; it++) {
        // ===== phase I: softmax + stage c*W in LDS + split-K MFMA GEMM =====
        // jobs: 32 k-splits (36 routes / 288 k) x 10 caps (16 jd each)
        for (int job = bid; job < KSPLIT * N_CAPS; job += GRID) {
            int ks = job % KSPLIT, ng = job / KSPLIT;
            int r0 = ks * 36, jd0 = ng * 16;
            __syncthreads();                 // LDS reuse across job loop
            if (it > 0 && t < 36) {          // softmax; keep only cap ng
                float bj[N_CAPS], m = -1e30f;
#pragma unroll
                for (int j = 0; j < N_CAPS; j++) { bj[j] = b_ij[(r0 + t) * N_CAPS + j]; m = fmaxf(m, bj[j]); }
                float sum = 0.f;
#pragma unroll
                for (int j = 0; j < N_CAPS; j++) { bj[j] = expf(bj[j] - m); sum += bj[j]; }
                cs36[t] = bj[ng] / sum;
            }
            __syncthreads();
            // stage 36 routes x 16 jd of c*W (hi/lo): 576 pairs, 8 floats each
            for (int p = t; p < 576; p += 256) {
                int rl = p >> 4, jdl = p & 15;
                const float* wp = W + ((size_t)(r0 + rl) * JD + jd0 + jdl) * C_IN;
                float c = (it == 0) ? 0.1f : cs36[rl];
                short8 vh, vl;
#pragma unroll
                for (int i = 0; i < 8; i++) {
                    float cw = wp[i] * c;
                    unsigned short hi = f2bf(cw);
                    vh[i] = (short)hi;
                    vl[i] = (short)f2bf(cw - bf2f(hi));
                }
                *(short8*)&bhs[jdl][rl * 8] = vh;    // k_local = rl*8+c, 16B aligned
                *(short8*)&bls[jdl][rl * 8] = vl;
            }
            __syncthreads();
            int w = t >> 6, l = t & 63, row = l & 15, quad = l >> 4;
            const short8* pah0 = (const short8*)(xh + (size_t)(w * 16 + row) * KK + ks * 288);
            const short8* pal0 = (const short8*)(xl + (size_t)(w * 16 + row) * KK + ks * 288);
            const short8* pah1 = (const short8*)(xh + (size_t)((w + 4) * 16 + row) * KK + ks * 288);
            const short8* pal1 = (const short8*)(xl + (size_t)((w + 4) * 16 + row) * KK + ks * 288);
            f32x4 acc0 = {0.f, 0.f, 0.f, 0.f}, acc1 = {0.f, 0.f, 0.f, 0.f};
#pragma unroll
            for (int st = 0; st < 9; st++) {
                short8 Bh = *(const short8*)&bhs[row][st * 32 + quad * 8];
                short8 Bl = *(const short8*)&bls[row][st * 32 + quad * 8];
                short8 Ah0 = pah0[st * 4 + quad], Al0 = pal0[st * 4 + quad];
                short8 Ah1 = pah1[st * 4 + quad], Al1 = pal1[st * 4 + quad];
                acc0 = __builtin_amdgcn_mfma_f32_16x16x32_bf16(Ah0, Bh, acc0, 0, 0, 0);
                acc0 = __builtin_amdgcn_mfma_f32_16x16x32_bf16(Ah0, Bl, acc0, 0, 0, 0);
                acc0 = __builtin_amdgcn_mfma_f32_16x16x32_bf16(Al0, Bh, acc0, 0, 0, 0);
                acc1 = __builtin_amdgcn_mfma_f32_16x16x32_bf16(Ah1, Bh, acc1, 0, 0, 0);
                acc1 = __builtin_amdgcn_mfma_f32_16x16x32_bf16(Ah1, Bl, acc1, 0, 0, 0);
                acc1 = __builtin_amdgcn_mfma_f32_16x16x32_bf16(Al1, Bh, acc1, 0, 0, 0);
            }
#pragma unroll
            for (int i = 0; i < 4; i++) {    // C/D: col=lane&15 (jd), row=quad*4+i (b)
                int b0 = w * 16 + quad * 4 + i;
                part[((size_t)(ks * B_BATCH + b0)) * JD + jd0 + row] = acc0[i];
                part[((size_t)(ks * B_BATCH + b0 + 64)) * JD + jd0 + row] = acc1[i];
            }
        }
        tgt += GRID; gridbar(cnt, tgt);

        // ============ phase R: reduce split-K + squash =====================
        if (bid < B_BATCH && t < JD) {
            int b = bid, jd = t;
            float acc = 0.f;
#pragma unroll 8
            for (int ks = 0; ks < KSPLIT; ks++)
                acc += part[((size_t)(ks * B_BATCH + b)) * JD + jd];
            float sq = acc * acc;            // lane%16 == jd%16 -> width-16 xor
#pragma unroll
            for (int off = 1; off < 16; off <<= 1) sq += __shfl_xor(sq, off, 16);
            float scale = sq / ((1.f + sq) * sqrtf(sq));
            float v = acc * scale;
            out[(size_t)b * JD + jd] = v;
            vb[(size_t)jd * B_BATCH + b] = f2bf(v);
        }
        if (it == 2) break;                  // final agreement not needed
        tgt += GRID; gridbar(cnt, tgt);

        // ====== phase A: M2 via MFMA + b_ij update; 288 jobs of 4 routes ===
        for (int job = bid; job < 288; job += GRID) {
            int r0 = job * 4, rc0 = job * 32;
            __syncthreads();                 // m2 reuse across job loop
            int w = t >> 6, l = t & 63, row = l & 15, quad = l >> 4;
            for (int u = w; u < 20; u += 4) {    // 2 m-tiles x 10 n-tiles
                int mt = u / 10, nt = u % 10;
                const short8* pa = (const short8*)(xT + (size_t)(rc0 + mt * 16 + row) * B_BATCH);
                const short8* pb = (const short8*)(vb + (size_t)(nt * 16 + row) * B_BATCH);
                f32x4 acc = {0.f, 0.f, 0.f, 0.f};
#pragma unroll
                for (int s = 0; s < 4; s++)  // K = 128
                    acc = __builtin_amdgcn_mfma_f32_16x16x32_bf16(pa[s * 4 + quad], pb[s * 4 + quad], acc, 0, 0, 0);
#pragma unroll
                for (int i = 0; i < 4; i++)  // C/D: col=jd, row=rc_local
                    m2[mt * 16 + quad * 4 + i][nt * 16 + row] = acc[i];
            }
            __syncthreads();
            for (int p = t; p < 640; p += 256) {  // 4 routes x 160 jd
                int rl = p / 160, jd = p % 160;
                const float* wp = W + ((size_t)(r0 + rl) * JD + jd) * C_IN;
                float a = 0.f;
#pragma unroll
                for (int c = 0; c < 8; c++)
                    a = fmaf(wp[c], m2[rl * 8 + c][jd], a);
#pragma unroll
                for (int off = 1; off < 16; off <<= 1) a += __shfl_xor(a, off, 16);
                if ((jd & 15) == 0)
                    b_ij[(r0 + rl) * N_CAPS + (jd >> 4)] += a * (1.f / B_BATCH);
            }
        }
        tgt += GRID; gridbar(cnt, tgt);
    }
}

extern "C" void kernel_launch(void* const* d_in, const int* in_sizes, int n_in,
                              void* d_out, int out_size, void* d_ws, size_t ws_size,
                              hipStream_t stream) {
    const float* x = (const float*)d_in[0];   // [128,1152,8]
    const float* W = (const float*)d_in[1];   // [1,1152,10,16,8]
    float* out = (float*)d_out;               // [128,10,16,1]
    char* ws = (char*)d_ws;

    float*          b_ij = (float*)(ws + 0);
    unsigned short* xh   = (unsigned short*)(ws + 46080);
    unsigned short* xl   = (unsigned short*)(ws + 2405376);
    unsigned short* xT   = (unsigned short*)(ws + 4764672);
    unsigned short* vb   = (unsigned short*)(ws + 7123968);
    float*          part = (float*)(ws + 7164928);
    unsigned int*   cnt  = (unsigned int*)(ws + 9786368);

    k_init<<<1, 64, 0, stream>>>(cnt);
    k_main<<<GRID, 256, 0, stream>>>(x, W, xh, xl, xT, b_ij, vb, part, out, cnt);
}

// Round 6
// 246.951 us; speedup vs baseline: 1.4737x; 1.4737x over previous
//
#include <hip/hip_runtime.h>
#include <math.h>

#define R_ROUTES 1152
#define N_CAPS 10
#define C_IN 8
#define D_DIM 16
#define B_BATCH 128
#define JD 160                      // N_CAPS * D_DIM
#define KK 9216                     // R_ROUTES * C_IN (GEMM K)
#define KSPLIT 32                   // 36 routes = 288 k per split
#define GRID 256                    // <= 1 block/CU: residency guaranteed

typedef __attribute__((ext_vector_type(8))) short short8;   // 8 bf16 (4 VGPRs)
typedef __attribute__((ext_vector_type(4))) float f32x4;    // MFMA accumulator

__device__ inline unsigned short f2bf(float f) {            // RNE fp32 -> bf16
    unsigned int u = __float_as_uint(f);
    unsigned int r = u + 0x7FFFu + ((u >> 16) & 1u);
    return (unsigned short)(r >> 16);
}
__device__ inline float bf2f(unsigned short h) {
    return __uint_as_float(((unsigned int)h) << 16);
}

// Device-scope grid barrier, cache-friendly protocol:
//  - arrival: RELEASE fetch_add (flushes this block's stores; one wb per block)
//  - spin:    RELAXED atomic loads (plain coherent-point load, NO buffer_inv;
//             R5's ACQUIRE-per-poll invalidated L2 chip-wide every ~0.2us and
//             destroyed concurrent blocks' locality: 316us, VALUBusy 1%)
//  - exit:    single ACQUIRE fence (one buffer_inv per block per barrier)
__device__ inline void gridbar(unsigned int* cnt, unsigned int target) {
    __syncthreads();
    if (threadIdx.x == 0) {
        __hip_atomic_fetch_add(cnt, 1u, __ATOMIC_RELEASE, __HIP_MEMORY_SCOPE_AGENT);
        while (__hip_atomic_load(cnt, __ATOMIC_RELAXED, __HIP_MEMORY_SCOPE_AGENT) < target)
            __builtin_amdgcn_s_sleep(16);
        __builtin_amdgcn_fence(__ATOMIC_ACQUIRE, "agent");
    }
    __syncthreads();
}

// ---------------------------------------------------------------------------
// ws layout (byte offsets):
//   b_ij fp32 [1152][10]      @ 0
//   xh   bf16 [128][9216]     @ 46080      A-layout [b][k]
//   xl   bf16 [128][9216]     @ 2405376
//   xT   bf16 [9216][128]     @ 4764672    A-layout for agree ([rc][b])
//   vb   bf16 [160][128]      @ 7123968    B-layout for agree ([jd][b])
//   part fp32 [32][128][160]  @ 7164928    split-K partials (2.6 MB)
//   cnt  u32                  @ 9786368    grid-barrier counter
// Everything written before read each launch; cnt zeroed by k_init.
// ---------------------------------------------------------------------------

__global__ void k_init(unsigned int* cnt) {
    if (threadIdx.x == 0)
        __hip_atomic_store(cnt, 0u, __ATOMIC_RELAXED, __HIP_MEMORY_SCOPE_AGENT);
}

__global__ __launch_bounds__(256, 2) void k_main(
    const float* __restrict__ x, const float* __restrict__ W,
    unsigned short* __restrict__ xh, unsigned short* __restrict__ xl,
    unsigned short* __restrict__ xT, float* __restrict__ b_ij,
    unsigned short* __restrict__ vb, float* __restrict__ part,
    float* __restrict__ out, unsigned int* cnt) {
    int bid = blockIdx.x, t = threadIdx.x;
    __shared__ float tile[32][33];           // phase P
    __shared__ float cs36[36];               // phase I softmax (this block's cap)
    __shared__ unsigned short bhs[16][296];  // phase I staged c*W hi [jd_l][k_l]
    __shared__ unsigned short bls[16][296];
    __shared__ float m2[32][164];            // phase A M2 tile, +4 pad
    unsigned int tgt = 0;

    // ============ phase P: x -> bf16 hi/lo + transpose; zero b_ij ==========
    for (int job = bid; job < 1152; job += GRID) {
        int bx = job >> 2, by = job & 3;     // rc-tile 0..287, b-tile 0..3
        int tx = t & 31, ty = t >> 5;
        __syncthreads();                     // tile reuse across job loop
#pragma unroll
        for (int i = 0; i < 4; i++) {
            int row = ty + i * 8;            // b_local
            size_t idx = (size_t)(by * 32 + row) * KK + bx * 32 + tx;
            float v = x[idx];
            tile[row][tx] = v;
            unsigned short hi = f2bf(v);
            xh[idx] = hi;
            xl[idx] = f2bf(v - bf2f(hi));
        }
        __syncthreads();
#pragma unroll
        for (int i = 0; i < 4; i++) {
            int row = ty + i * 8;            // rc_local
            xT[(size_t)(bx * 32 + row) * B_BATCH + by * 32 + tx] = f2bf(tile[tx][row]);
        }
    }
    if (bid < 45) b_ij[bid * 256 + t] = 0.f; // 45*256 == 11520
    tgt += GRID; gridbar(cnt, tgt);

    for (int it = 0; it < 3; it++) {
        // ===== phase I: softmax + stage c*W in LDS + split-K MFMA GEMM =====
        // jobs: 32 k-splits (36 routes / 288 k) x 10 caps (16 jd each)
        for (int job = bid; job < KSPLIT * N_CAPS; job += GRID) {
            int ks = job % KSPLIT, ng = job / KSPLIT;
            int r0 = ks * 36, jd0 = ng * 16;
            __syncthreads();                 // LDS reuse across job loop
            if (it > 0 && t < 36) {          // softmax; keep only cap ng
                float bj[N_CAPS], m = -1e30f;
#pragma unroll
                for (int j = 0; j < N_CAPS; j++) { bj[j] = b_ij[(r0 + t) * N_CAPS + j]; m = fmaxf(m, bj[j]); }
                float sum = 0.f;
#pragma unroll
                for (int j = 0; j < N_CAPS; j++) { bj[j] = expf(bj[j] - m); sum += bj[j]; }
                cs36[t] = bj[ng] / sum;
            }
            __syncthreads();
            // stage 36 routes x 16 jd of c*W (hi/lo): 576 pairs, 8 floats each
            for (int p = t; p < 576; p += 256) {
                int rl = p >> 4, jdl = p & 15;
                const float* wp = W + ((size_t)(r0 + rl) * JD + jd0 + jdl) * C_IN;
                float c = (it == 0) ? 0.1f : cs36[rl];
                short8 vh, vl;
#pragma unroll
                for (int i = 0; i < 8; i++) {
                    float cw = wp[i] * c;
                    unsigned short hi = f2bf(cw);
                    vh[i] = (short)hi;
                    vl[i] = (short)f2bf(cw - bf2f(hi));
                }
                *(short8*)&bhs[jdl][rl * 8] = vh;    // k_local = rl*8+c, 16B aligned
                *(short8*)&bls[jdl][rl * 8] = vl;
            }
            __syncthreads();
            int w = t >> 6, l = t & 63, row = l & 15, quad = l >> 4;
            const short8* pah0 = (const short8*)(xh + (size_t)(w * 16 + row) * KK + ks * 288);
            const short8* pal0 = (const short8*)(xl + (size_t)(w * 16 + row) * KK + ks * 288);
            const short8* pah1 = (const short8*)(xh + (size_t)((w + 4) * 16 + row) * KK + ks * 288);
            const short8* pal1 = (const short8*)(xl + (size_t)((w + 4) * 16 + row) * KK + ks * 288);
            f32x4 acc0 = {0.f, 0.f, 0.f, 0.f}, acc1 = {0.f, 0.f, 0.f, 0.f};
#pragma unroll
            for (int st = 0; st < 9; st++) {
                short8 Bh = *(const short8*)&bhs[row][st * 32 + quad * 8];
                short8 Bl = *(const short8*)&bls[row][st * 32 + quad * 8];
                short8 Ah0 = pah0[st * 4 + quad], Al0 = pal0[st * 4 + quad];
                short8 Ah1 = pah1[st * 4 + quad], Al1 = pal1[st * 4 + quad];
                acc0 = __builtin_amdgcn_mfma_f32_16x16x32_bf16(Ah0, Bh, acc0, 0, 0, 0);
                acc0 = __builtin_amdgcn_mfma_f32_16x16x32_bf16(Ah0, Bl, acc0, 0, 0, 0);
                acc0 = __builtin_amdgcn_mfma_f32_16x16x32_bf16(Al0, Bh, acc0, 0, 0, 0);
                acc1 = __builtin_amdgcn_mfma_f32_16x16x32_bf16(Ah1, Bh, acc1, 0, 0, 0);
                acc1 = __builtin_amdgcn_mfma_f32_16x16x32_bf16(Ah1, Bl, acc1, 0, 0, 0);
                acc1 = __builtin_amdgcn_mfma_f32_16x16x32_bf16(Al1, Bh, acc1, 0, 0, 0);
            }
#pragma unroll
            for (int i = 0; i < 4; i++) {    // C/D: col=lane&15 (jd), row=quad*4+i (b)
                int b0 = w * 16 + quad * 4 + i;
                part[((size_t)(ks * B_BATCH + b0)) * JD + jd0 + row] = acc0[i];
                part[((size_t)(ks * B_BATCH + b0 + 64)) * JD + jd0 + row] = acc1[i];
            }
        }
        tgt += GRID; gridbar(cnt, tgt);

        // ============ phase R: reduce split-K + squash =====================
        if (bid < B_BATCH && t < JD) {
            int b = bid, jd = t;
            float acc = 0.f;
#pragma unroll 8
            for (int ks = 0; ks < KSPLIT; ks++)
                acc += part[((size_t)(ks * B_BATCH + b)) * JD + jd];
            float sq = acc * acc;            // lane%16 == jd%16 -> width-16 xor
#pragma unroll
            for (int off = 1; off < 16; off <<= 1) sq += __shfl_xor(sq, off, 16);
            float scale = sq / ((1.f + sq) * sqrtf(sq));
            float v = acc * scale;
            out[(size_t)b * JD + jd] = v;
            vb[(size_t)jd * B_BATCH + b] = f2bf(v);
        }
        if (it == 2) break;                  // final agreement not needed
        tgt += GRID; gridbar(cnt, tgt);

        // ====== phase A: M2 via MFMA + b_ij update; 288 jobs of 4 routes ===
        for (int job = bid; job < 288; job += GRID) {
            int r0 = job * 4, rc0 = job * 32;
            __syncthreads();                 // m2 reuse across job loop
            int w = t >> 6, l = t & 63, row = l & 15, quad = l >> 4;
            for (int u = w; u < 20; u += 4) {    // 2 m-tiles x 10 n-tiles
                int mt = u / 10, nt = u % 10;
                const short8* pa = (const short8*)(xT + (size_t)(rc0 + mt * 16 + row) * B_BATCH);
                const short8* pb = (const short8*)(vb + (size_t)(nt * 16 + row) * B_BATCH);
                f32x4 acc = {0.f, 0.f, 0.f, 0.f};
#pragma unroll
                for (int s = 0; s < 4; s++)  // K = 128
                    acc = __builtin_amdgcn_mfma_f32_16x16x32_bf16(pa[s * 4 + quad], pb[s * 4 + quad], acc, 0, 0, 0);
#pragma unroll
                for (int i = 0; i < 4; i++)  // C/D: col=jd, row=rc_local
                    m2[mt * 16 + quad * 4 + i][nt * 16 + row] = acc[i];
            }
            __syncthreads();
            for (int p = t; p < 640; p += 256) {  // 4 routes x 160 jd
                int rl = p / 160, jd = p % 160;
                const float* wp = W + ((size_t)(r0 + rl) * JD + jd) * C_IN;
                float a = 0.f;
#pragma unroll
                for (int c = 0; c < 8; c++)
                    a = fmaf(wp[c], m2[rl * 8 + c][jd], a);
#pragma unroll
                for (int off = 1; off < 16; off <<= 1) a += __shfl_xor(a, off, 16);
                if ((jd & 15) == 0)
                    b_ij[(r0 + rl) * N_CAPS + (jd >> 4)] += a * (1.f / B_BATCH);
            }
        }
        tgt += GRID; gridbar(cnt, tgt);
    }
}

extern "C" void kernel_launch(void* const* d_in, const int* in_sizes, int n_in,
                              void* d_out, int out_size, void* d_ws, size_t ws_size,
                              hipStream_t stream) {
    const float* x = (const float*)d_in[0];   // [128,1152,8]
    const float* W = (const float*)d_in[1];   // [1,1152,10,16,8]
    float* out = (float*)d_out;               // [128,10,16,1]
    char* ws = (char*)d_ws;

    float*          b_ij = (float*)(ws + 0);
    unsigned short* xh   = (unsigned short*)(ws + 46080);
    unsigned short* xl   = (unsigned short*)(ws + 2405376);
    unsigned short* xT   = (unsigned short*)(ws + 4764672);
    unsigned short* vb   = (unsigned short*)(ws + 7123968);
    float*          part = (float*)(ws + 7164928);
    unsigned int*   cnt  = (unsigned int*)(ws + 9786368);

    k_init<<<1, 64, 0, stream>>>(cnt);
    k_main<<<GRID, 256, 0, stream>>>(x, W, xh, xl, xT, b_ij, vb, part, out, cnt);
}

// Round 7
// 113.402 us; speedup vs baseline: 3.2093x; 2.1777x over previous
//
#include <hip/hip_runtime.h>
#include <math.h>

#define R_ROUTES 1152
#define N_CAPS 10
#define C_IN 8
#define D_DIM 16
#define B_BATCH 128
#define JD 160                      // N_CAPS * D_DIM
#define KK 9216                     // R_ROUTES * C_IN (GEMM K)
#define KSPLIT 48                   // 24 routes = 192 k per split
#define RS 24                       // routes per k-split
#define NG 5                        // jd groups of 32

typedef __attribute__((ext_vector_type(8))) short short8;   // 8 bf16 (4 VGPRs)
typedef __attribute__((ext_vector_type(4))) float f32x4;    // MFMA accumulator

__device__ inline unsigned short f2bf(float f) {            // RNE fp32 -> bf16
    unsigned int u = __float_as_uint(f);
    unsigned int r = u + 0x7FFFu + ((u >> 16) & 1u);
    return (unsigned short)(r >> 16);
}
__device__ inline float bf2f(unsigned short h) {
    return __uint_as_float(((unsigned int)h) << 16);
}

// ---------------------------------------------------------------------------
// ws layout (byte offsets):
//   b_ij fp32 [1152][10]       @ 0         (46080 B)
//   s0/s1/s2 fp32 [128][160]   @ 46080     (3 x 81920 B, contiguous)
//   xh   bf16 [128][9216]      @ 292096    A-layout [b][k]
//   xl   bf16 [128][9216]      @ 2651392
//   xT   bf16 [9216][128]      @ 5010688   A-layout for k_va ([rc][b])
// total ~7.4 MB. Everything written before read each launch (re-poison safe).
// Lesson log: R5/R6 showed in-kernel grid barriers cost ~20us each (agent-
// scope inv/wb storms); dispatch boundaries are ~2-3us -> multi-dispatch.
// ---------------------------------------------------------------------------

// prep: x -> bf16 hi/lo + transpose; zero b_ij and s0..s2
__global__ __launch_bounds__(256) void k_prep(
    const float* __restrict__ x, unsigned short* __restrict__ xh,
    unsigned short* __restrict__ xl, unsigned short* __restrict__ xT,
    float* __restrict__ b_ij, float* __restrict__ s_all) {
    __shared__ float tile[32][33];
    int bx = blockIdx.x;            // rc tile 0..287
    int by = blockIdx.y;            // b tile 0..3
    int t = threadIdx.x;
    int tx = t & 31, ty = t >> 5;
#pragma unroll
    for (int i = 0; i < 4; i++) {
        int row = ty + i * 8;       // b_local
        size_t idx = (size_t)(by * 32 + row) * KK + bx * 32 + tx;
        float v = x[idx];
        tile[row][tx] = v;
        unsigned short hi = f2bf(v);
        xh[idx] = hi;
        xl[idx] = f2bf(v - bf2f(hi));
    }
    __syncthreads();
#pragma unroll
    for (int i = 0; i < 4; i++) {
        int row = ty + i * 8;       // rc_local
        xT[(size_t)(bx * 32 + row) * B_BATCH + by * 32 + tx] = f2bf(tile[tx][row]);
    }
    int bid = by * 288 + bx;        // 0..1151
    if (bid < 240) s_all[bid * 256 + t] = 0.f;              // 240*256 == 61440
    else if (bid < 285) b_ij[(bid - 240) * 256 + t] = 0.f;  // 45*256 == 11520
}

// Fused GEMM iteration: softmax(b_ij) -> c, stage c*W (bf16 hi/lo) in LDS,
// MFMA over this block's 192-k x 32-jd range, atomicAdd partials into s.
// Grid (48, 5), block 256.
template <bool FIRST>
__global__ __launch_bounds__(256) void k_iter(
    const unsigned short* __restrict__ xh, const unsigned short* __restrict__ xl,
    const float* __restrict__ W, const float* __restrict__ b_ij,
    float* __restrict__ s) {
    __shared__ float cs[RS][N_CAPS];
    __shared__ unsigned short bhs[32][200];   // [jd_l][k_l], stride 400B (16B-mult)
    __shared__ unsigned short bls[32][200];
    int t = threadIdx.x;
    int ks = blockIdx.x, ng = blockIdx.y;
    int r0 = ks * RS, jd0 = ng * 32;

    if (!FIRST && t < RS) {          // softmax for this block's routes
        float bj[N_CAPS], m = -1e30f;
#pragma unroll
        for (int j = 0; j < N_CAPS; j++) { bj[j] = b_ij[(r0 + t) * N_CAPS + j]; m = fmaxf(m, bj[j]); }
        float sum = 0.f;
#pragma unroll
        for (int j = 0; j < N_CAPS; j++) { bj[j] = expf(bj[j] - m); sum += bj[j]; }
        float inv = 1.f / sum;
#pragma unroll
        for (int j = 0; j < N_CAPS; j++) cs[t][j] = bj[j] * inv;
    }
    __syncthreads();

    // stage 24 routes x 32 jd of c*W (hi/lo): 768 pairs, 8 fp32 each
#pragma unroll
    for (int p = t; p < RS * 32; p += 256) {
        int rl = p >> 5, jdl = p & 31;
        const float* wp = W + ((size_t)(r0 + rl) * JD + jd0 + jdl) * C_IN;
        float c = FIRST ? 0.1f : cs[rl][(jd0 + jdl) >> 4];
        short8 vh, vl;
#pragma unroll
        for (int i = 0; i < 8; i++) {
            float cw = wp[i] * c;
            unsigned short hi = f2bf(cw);
            vh[i] = (short)hi;
            vl[i] = (short)f2bf(cw - bf2f(hi));
        }
        *(short8*)&bhs[jdl][rl * 8] = vh;    // k_local = rl*8+i
        *(short8*)&bls[jdl][rl * 8] = vl;
    }
    __syncthreads();

    int w = t >> 6, l = t & 63, row = l & 15, quad = l >> 4;
    const short8* pah0 = (const short8*)(xh + (size_t)(w * 16 + row) * KK + ks * 192);
    const short8* pal0 = (const short8*)(xl + (size_t)(w * 16 + row) * KK + ks * 192);
    const short8* pah1 = (const short8*)(xh + (size_t)((w + 4) * 16 + row) * KK + ks * 192);
    const short8* pal1 = (const short8*)(xl + (size_t)((w + 4) * 16 + row) * KK + ks * 192);
    f32x4 a00 = {0,0,0,0}, a01 = {0,0,0,0}, a10 = {0,0,0,0}, a11 = {0,0,0,0};
#pragma unroll
    for (int st = 0; st < 6; st++) {         // K = 192 = 6 steps of 32
        short8 Bh0 = *(const short8*)&bhs[row][st * 32 + quad * 8];
        short8 Bl0 = *(const short8*)&bls[row][st * 32 + quad * 8];
        short8 Bh1 = *(const short8*)&bhs[16 + row][st * 32 + quad * 8];
        short8 Bl1 = *(const short8*)&bls[16 + row][st * 32 + quad * 8];
        short8 Ah0 = pah0[st * 4 + quad], Al0 = pal0[st * 4 + quad];
        short8 Ah1 = pah1[st * 4 + quad], Al1 = pal1[st * 4 + quad];
        a00 = __builtin_amdgcn_mfma_f32_16x16x32_bf16(Ah0, Bh0, a00, 0, 0, 0);
        a00 = __builtin_amdgcn_mfma_f32_16x16x32_bf16(Ah0, Bl0, a00, 0, 0, 0);
        a00 = __builtin_amdgcn_mfma_f32_16x16x32_bf16(Al0, Bh0, a00, 0, 0, 0);
        a01 = __builtin_amdgcn_mfma_f32_16x16x32_bf16(Ah0, Bh1, a01, 0, 0, 0);
        a01 = __builtin_amdgcn_mfma_f32_16x16x32_bf16(Ah0, Bl1, a01, 0, 0, 0);
        a01 = __builtin_amdgcn_mfma_f32_16x16x32_bf16(Al0, Bh1, a01, 0, 0, 0);
        a10 = __builtin_amdgcn_mfma_f32_16x16x32_bf16(Ah1, Bh0, a10, 0, 0, 0);
        a10 = __builtin_amdgcn_mfma_f32_16x16x32_bf16(Ah1, Bl0, a10, 0, 0, 0);
        a10 = __builtin_amdgcn_mfma_f32_16x16x32_bf16(Al1, Bh0, a10, 0, 0, 0);
        a11 = __builtin_amdgcn_mfma_f32_16x16x32_bf16(Ah1, Bh1, a11, 0, 0, 0);
        a11 = __builtin_amdgcn_mfma_f32_16x16x32_bf16(Ah1, Bl1, a11, 0, 0, 0);
        a11 = __builtin_amdgcn_mfma_f32_16x16x32_bf16(Al1, Bh1, a11, 0, 0, 0);
    }
#pragma unroll
    for (int i = 0; i < 4; i++) {            // C/D: col=lane&15 (jd), row=quad*4+i (b)
        int b0 = w * 16 + quad * 4 + i, b1 = b0 + 64;
        atomicAdd(&s[(size_t)b0 * JD + jd0 + row],      a00[i]);
        atomicAdd(&s[(size_t)b0 * JD + jd0 + 16 + row], a01[i]);
        atomicAdd(&s[(size_t)b1 * JD + jd0 + row],      a10[i]);
        atomicAdd(&s[(size_t)b1 * JD + jd0 + 16 + row], a11[i]);
    }
}

// Fused squash + agreement: read s (80KB), squash -> v (bf16) in LDS,
// M2 tile (32 rc x 160 jd) via MFMA, b_ij update. Block owns 4 routes.
__global__ __launch_bounds__(256) void k_va(
    const unsigned short* __restrict__ xT, const float* __restrict__ s,
    const float* __restrict__ W, float* __restrict__ b_ij) {
    __shared__ unsigned short vb[JD][136];   // [jd][b], +8 pad (272B, 16B-mult)
    __shared__ float m2[32][164];            // [rc_local][jd], +4 pad
    int t = threadIdx.x;
    int r0 = blockIdx.x * 4, rc0 = blockIdx.x * 32;

    // squash: 1280 (b,j) pairs, 5 per thread, 16 contiguous floats each
#pragma unroll
    for (int q = 0; q < 5; q++) {
        int pi = t * 5 + q;                  // (b, j) pair
        int b = pi / N_CAPS, j = pi % N_CAPS;
        const float* sp = s + (size_t)b * JD + j * D_DIM;
        float sv[D_DIM], sqn = 0.f;
#pragma unroll
        for (int d = 0; d < D_DIM; d++) { sv[d] = sp[d]; sqn = fmaf(sv[d], sv[d], sqn); }
        float scale = sqn / ((1.f + sqn) * sqrtf(sqn));
#pragma unroll
        for (int d = 0; d < D_DIM; d++)
            vb[j * D_DIM + d][b] = f2bf(sv[d] * scale);
    }
    __syncthreads();

    int w = t >> 6, l = t & 63, row = l & 15, quad = l >> 4;
    for (int u = w; u < 20; u += 4) {        // 2 m-tiles x 10 n-tiles
        int mt = u / 10, nt = u % 10;
        const short8* pa = (const short8*)(xT + (size_t)(rc0 + mt * 16 + row) * B_BATCH);
        f32x4 acc = {0,0,0,0};
#pragma unroll
        for (int st = 0; st < 4; st++) {     // K = 128 = 4 steps of 32
            short8 Bv = *(const short8*)&vb[nt * 16 + row][st * 32 + quad * 8];
            acc = __builtin_amdgcn_mfma_f32_16x16x32_bf16(pa[st * 4 + quad], Bv, acc, 0, 0, 0);
        }
#pragma unroll
        for (int i = 0; i < 4; i++)          // C/D: col=jd, row=rc_local
            m2[mt * 16 + quad * 4 + i][nt * 16 + row] = acc[i];
    }
    __syncthreads();

    for (int p = t; p < 640; p += 256) {     // 4 routes x 160 jd
        int rl = p / JD, jd = p % JD;
        const float* wp = W + ((size_t)(r0 + rl) * JD + jd) * C_IN;
        float a = 0.f;
#pragma unroll
        for (int c = 0; c < C_IN; c++)
            a = fmaf(wp[c], m2[rl * 8 + c][jd], a);
#pragma unroll
        for (int off = 1; off < 16; off <<= 1) a += __shfl_xor(a, off, 16);
        if ((jd & 15) == 0)
            b_ij[(r0 + rl) * N_CAPS + (jd >> 4)] += a * (1.f / B_BATCH);
    }
}

// final: squash s2 -> out
__global__ __launch_bounds__(320) void k_rs_final(
    const float* __restrict__ s, float* __restrict__ out) {
    int t = threadIdx.x;                     // 320 = 2 b x 160 jd
    int bloc = t / JD, jd = t % JD;
    int b = blockIdx.x * 2 + bloc;
    float acc = s[(size_t)b * JD + jd];
    float sq = acc * acc;                    // lane%16 == jd%16 -> width-16 xor
#pragma unroll
    for (int off = 1; off < 16; off <<= 1) sq += __shfl_xor(sq, off, 16);
    float scale = sq / ((1.f + sq) * sqrtf(sq));
    out[(size_t)b * JD + jd] = acc * scale;
}

extern "C" void kernel_launch(void* const* d_in, const int* in_sizes, int n_in,
                              void* d_out, int out_size, void* d_ws, size_t ws_size,
                              hipStream_t stream) {
    const float* x = (const float*)d_in[0];   // [128,1152,8]
    const float* W = (const float*)d_in[1];   // [1,1152,10,16,8]
    float* out = (float*)d_out;               // [128,10,16,1]
    char* ws = (char*)d_ws;

    float*          b_ij = (float*)(ws + 0);
    float*          s0   = (float*)(ws + 46080);
    float*          s1   = (float*)(ws + 46080 + 81920);
    float*          s2   = (float*)(ws + 46080 + 163840);
    unsigned short* xh   = (unsigned short*)(ws + 292096);
    unsigned short* xl   = (unsigned short*)(ws + 2651392);
    unsigned short* xT   = (unsigned short*)(ws + 5010688);

    k_prep<<<dim3(288, 4), 256, 0, stream>>>(x, xh, xl, xT, b_ij, s0);

    k_iter<true><<<dim3(KSPLIT, NG), 256, 0, stream>>>(xh, xl, W, b_ij, s0);
    k_va<<<288, 256, 0, stream>>>(xT, s0, W, b_ij);

    k_iter<false><<<dim3(KSPLIT, NG), 256, 0, stream>>>(xh, xl, W, b_ij, s1);
    k_va<<<288, 256, 0, stream>>>(xT, s1, W, b_ij);

    k_iter<false><<<dim3(KSPLIT, NG), 256, 0, stream>>>(xh, xl, W, b_ij, s2);
    k_rs_final<<<64, 320, 0, stream>>>(s2, out);
}